// Round 9
// baseline (828.855 us; speedup 1.0000x reference)
//
#include <hip/hip_runtime.h>
#include <hip/hip_bf16.h>

#define NROWS 8192
#define DDIM 768

typedef short short8 __attribute__((ext_vector_type(8)));   // 8 x bf16 (4 VGPRs)
typedef float floatx4 __attribute__((ext_vector_type(4)));  // MFMA C/D

// ---------------------------------------------------------------------------
// Kernel 1: row-normalize features (fp32 in) -> bf16 normalized rows
// ---------------------------------------------------------------------------
__global__ __launch_bounds__(256) void normalize_k(const float* __restrict__ f,
                                                   __hip_bfloat16* __restrict__ fn) {
    const int row = blockIdx.x;
    const int t = threadIdx.x;
    const float* fr = f + (size_t)row * DDIM;
    float v0 = fr[t];
    float v1 = fr[t + 256];
    float v2 = fr[t + 512];
    float ss = v0 * v0 + v1 * v1 + v2 * v2;
#pragma unroll
    for (int m = 32; m; m >>= 1) ss += __shfl_xor(ss, m, 64);
    __shared__ float wsum[4];
    if ((t & 63) == 0) wsum[t >> 6] = ss;
    __syncthreads();
    float tot = wsum[0] + wsum[1] + wsum[2] + wsum[3];
    float inv = 1.0f / fmaxf(sqrtf(tot), 1e-8f);
    __hip_bfloat16* o = fn + (size_t)row * DDIM;
    o[t]       = __float2bfloat16(v0 * inv);
    o[t + 256] = __float2bfloat16(v1 * inv);
    o[t + 512] = __float2bfloat16(v2 * inv);
}

// ---------------------------------------------------------------------------
// Kernel 2: SYMMETRIC bf16 GEMM (s = 10 * fn fn^T) + fused mask reductions.
// R9: mirror epilogue fused elementwise into the direct one — no LDS
// transpose, no strip barriers, exp computed ONCE per element. Per acc
// element (i,j): direct accumulates into row i (mask[i][j], float4 loads),
// mirror into row j (mask[j][i], dword loads = 4x64B segments/instr).
// Loop mf-outer/nf-inner keeps mirror accs at 12 VGPRs (per-reg).
// K-loop identical to R5/R7 win config (BK=32, XOR swizzle, (256,4)).
// D[m=j][n=i]: j = colBase+wm*64+mf*16+q*4+reg, i = rowBase+wn*64+nf*16+cl.
// ---------------------------------------------------------------------------
__global__ __launch_bounds__(256, 4) void ntxent_main(
        const __hip_bfloat16* __restrict__ fn,
        const float* __restrict__ pmask, const float* __restrict__ nmask,
        float* __restrict__ negG, float* __restrict__ sG,
        float* __restrict__ pG) {
    __shared__ __hip_bfloat16 Is[128 * 32];   // 8 KB
    __shared__ __hip_bfloat16 Js[128 * 32];   // 8 KB

    const int t = threadIdx.x;
    const int lane = t & 63;
    const int wv = t >> 6;
    const int wm = wv & 1;           // wave's j-half
    const int wn = wv >> 1;          // wave's i-half
    const int q  = lane >> 4;
    const int cl = lane & 15;

    // triangular decode: block bt -> (c, r) with c <= r
    const int bt = blockIdx.x;
    int r = (int)((sqrtf(8.0f * (float)bt + 1.0f) - 1.0f) * 0.5f);
    while ((r + 1) * (r + 2) / 2 <= bt) ++r;
    while (r * (r + 1) / 2 > bt) --r;
    const int c = bt - r * (r + 1) / 2;
    const int rowBase = c * 128;     // i-tile
    const int colBase = r * 128;     // j-tile
    const bool offDiag = (c != r);

    const int rdSw = ((q ^ ((cl >> 1) & 3)) << 4);

    floatx4 acc[4][4];            // [mf (j)][nf (i)]
#pragma unroll
    for (int mf = 0; mf < 4; ++mf)
#pragma unroll
        for (int nf = 0; nf < 4; ++nf)
            acc[mf][nf] = (floatx4){0.f, 0.f, 0.f, 0.f};

    for (int k0 = 0; k0 < DDIM; k0 += 32) {
        __syncthreads();
#pragma unroll
        for (int it = 0; it < 2; ++it) {
            const int s = it * 256 + t;              // 16B slot 0..511
            const int rr = s >> 2;
            const int cg = (s & 3) ^ ((rr >> 1) & 3); // swizzled src chunk
            const __hip_bfloat16* ga = fn + (size_t)(rowBase + rr) * DDIM + k0 + cg * 8;
            const __hip_bfloat16* gb = fn + (size_t)(colBase + rr) * DDIM + k0 + cg * 8;
            __builtin_amdgcn_global_load_lds(
                (const __attribute__((address_space(1))) void*)ga,
                (__attribute__((address_space(3))) void*)((char*)Is + s * 16), 16, 0, 0);
            __builtin_amdgcn_global_load_lds(
                (const __attribute__((address_space(1))) void*)gb,
                (__attribute__((address_space(3))) void*)((char*)Js + s * 16), 16, 0, 0);
        }
        __syncthreads();

        short8 jf[4], if_[4];
#pragma unroll
        for (int mf = 0; mf < 4; ++mf) {
            const int rr = wm * 64 + mf * 16 + cl;
            jf[mf] = *(const short8*)((const char*)Js + rr * 64 + rdSw);
        }
#pragma unroll
        for (int nf = 0; nf < 4; ++nf) {
            const int rr = wn * 64 + nf * 16 + cl;
            if_[nf] = *(const short8*)((const char*)Is + rr * 64 + rdSw);
        }
#pragma unroll
        for (int mf = 0; mf < 4; ++mf)
#pragma unroll
            for (int nf = 0; nf < 4; ++nf)
                acc[mf][nf] = __builtin_amdgcn_mfma_f32_16x16x32_bf16(
                    jf[mf], if_[nf], acc[mf][nf], 0, 0, 0);
    }

    // ---- fused epilogue: direct (rows i) + mirror (rows j), no LDS ----
    const int col64 = colBase + wm * 64;
    const int jb0 = col64 + q * 4;            // direct j-float4 base (+ mf*16)
    const int ibase = rowBase + wn * 64;      // this wave's i range (+ nf*16 + cl)

    float dN[4], dS[4], dP[4];                // direct accs per nf (row i)
#pragma unroll
    for (int nf = 0; nf < 4; ++nf) { dN[nf] = 0.f; dS[nf] = 0.f; dP[nf] = 0.f; }

#pragma unroll
    for (int mf = 0; mf < 4; ++mf) {
        const int jbase = jb0 + mf * 16;      // 4 consecutive j for this lane
        float mN[4], mS[4], mP[4];            // mirror accs per reg (row j)
#pragma unroll
        for (int g = 0; g < 4; ++g) { mN[g] = 0.f; mS[g] = 0.f; mP[g] = 0.f; }

#pragma unroll
        for (int nf = 0; nf < 4; ++nf) {
            const int grow = ibase + nf * 16 + cl;
            // direct masks: mask[i=grow][jbase..jbase+3]  (float4)
            float4 pd = *(const float4*)(pmask + (size_t)grow * NROWS + jbase);
            float4 nd = *(const float4*)(nmask + (size_t)grow * NROWS + jbase);
            // mirror masks: mask[j=jbase+reg][grow]  (dword, 4x64B segments)
            float pmm[4], nmm[4];
            if (offDiag) {
#pragma unroll
                for (int g = 0; g < 4; ++g) {
                    const size_t mo = (size_t)(jbase + g) * NROWS + grow;
                    pmm[g] = pmask[mo];
                    nmm[g] = nmask[mo];
                }
            }
#pragma unroll
            for (int g = 0; g < 4; ++g) {
                float pdv = ((const float*)&pd)[g];
                float ndv = ((const float*)&nd)[g];
                if (!offDiag && grow == jbase + g) { pdv = 0.f; ndv = 0.f; }
                float v = acc[mf][nf][g];
                float e = __builtin_amdgcn_exp2f(v * 14.4269504089f); // e^(10v)
                dN[nf] = fmaf(ndv, e, dN[nf]);
                dS[nf] = fmaf(pdv, v, dS[nf]);     // raw units; x10 in final_k
                dP[nf] += pdv;
                if (offDiag) {
                    mN[g] = fmaf(nmm[g], e, mN[g]);
                    mS[g] = fmaf(pmm[g], v, mS[g]);
                    mP[g] += pmm[g];
                }
            }
        }
        if (offDiag) {
            // reduce mirror accs across the 16 cl lanes of each q-group
#pragma unroll
            for (int g = 0; g < 4; ++g) {
#pragma unroll
                for (int m = 1; m < 16; m <<= 1) {
                    mN[g] += __shfl_xor(mN[g], m, 64);
                    mS[g] += __shfl_xor(mS[g], m, 64);
                    mP[g] += __shfl_xor(mP[g], m, 64);
                }
            }
            if (cl == 0) {
#pragma unroll
                for (int g = 0; g < 4; ++g) {
                    const int jg = jbase + g;
                    atomicAdd(&negG[jg], mN[g]);
                    atomicAdd(&sG[jg],   mS[g]);
                    atomicAdd(&pG[jg],   mP[g]);
                }
            }
        }
    }

    // direct reduction: across the 4 q-groups (j sub-ranges)
#pragma unroll
    for (int nf = 0; nf < 4; ++nf) {
        dN[nf] += __shfl_xor(dN[nf], 16, 64);  dN[nf] += __shfl_xor(dN[nf], 32, 64);
        dS[nf] += __shfl_xor(dS[nf], 16, 64);  dS[nf] += __shfl_xor(dS[nf], 32, 64);
        dP[nf] += __shfl_xor(dP[nf], 16, 64);  dP[nf] += __shfl_xor(dP[nf], 32, 64);
        if (q == 0) {
            const int grow = ibase + nf * 16 + cl;
            atomicAdd(&negG[grow], dN[nf]);
            atomicAdd(&sG[grow],   dS[nf]);
            atomicAdd(&pG[grow],   dP[nf]);
        }
    }
}

// ---------------------------------------------------------------------------
// Kernel 3: per-row loss assembly + mean
// loss_i = (P*log(neg) - 10*S_raw)/P (P>0 else 0);  out = mean
// ---------------------------------------------------------------------------
__global__ __launch_bounds__(1024) void final_k(const float* __restrict__ negG,
        const float* __restrict__ sG, const float* __restrict__ pG,
        float* __restrict__ out) {
    const int t = threadIdx.x;
    float sum = 0.f;
    for (int i = t; i < NROWS; i += 1024) {
        float P = pG[i];
        if (P > 0.f) {
            sum += (P * logf(negG[i]) - 10.0f * sG[i]) / P;
        }
    }
#pragma unroll
    for (int m = 32; m; m >>= 1) sum += __shfl_xor(sum, m, 64);
    __shared__ float wsum[16];
    if ((t & 63) == 0) wsum[t >> 6] = sum;
    __syncthreads();
    if (t < 16) {
        float v = wsum[t];
#pragma unroll
        for (int m = 8; m; m >>= 1) v += __shfl_xor(v, m, 16);
        if (t == 0) out[0] = v / (float)NROWS;
    }
}

// ---------------------------------------------------------------------------
extern "C" void kernel_launch(void* const* d_in, const int* in_sizes, int n_in,
                              void* d_out, int out_size, void* d_ws, size_t ws_size,
                              hipStream_t stream) {
    const float* feat  = (const float*)d_in[0];
    const float* pmask = (const float*)d_in[1];
    const float* nmask = (const float*)d_in[2];
    float* out = (float*)d_out;

    char* ws = (char*)d_ws;
    __hip_bfloat16* fn = (__hip_bfloat16*)ws;                    // 12,582,912 B
    float* negG = (float*)(ws + 12582912);
    float* sG = negG + NROWS;
    float* pG = sG + NROWS;

    // zero all three row accumulators (ws is re-poisoned before every launch)
    hipMemsetAsync(negG, 0, 3 * NROWS * sizeof(float), stream);

    normalize_k<<<NROWS, 256, 0, stream>>>(feat, fn);

    ntxent_main<<<2080, 256, 0, stream>>>(fn, pmask, nmask, negG, sG, pG);

    final_k<<<1, 1024, 0, stream>>>(negG, sG, pG, out);
}

// Round 10
// 590.625 us; speedup vs baseline: 1.4034x; 1.4034x over previous
//
#include <hip/hip_runtime.h>
#include <hip/hip_bf16.h>

#define NROWS 8192
#define DDIM 768

typedef float floatx4 __attribute__((ext_vector_type(4)));  // MFMA C/D
typedef long i64;                                           // fp8 MFMA A/B frag
#define TSTRIDE 132   // transpose LDS row stride (floats)
// acc holds 256*sim (fn scaled by 16 per side). e^(10*sim) = exp2(acc*EK):
#define EK 0.05635527503472514f      // = log2(e) * 10 / 256
#define SSCALE 0.390625f             // = 10 / 256 (applied in final_k)

// ---------------------------------------------------------------------------
// Kernel 1: row-normalize features (fp32 in) -> fp8 e4m3 rows, scaled x16
// 256 thr/row; threads 0..191 each own one float4 (768 = 192*4)
// ---------------------------------------------------------------------------
__global__ __launch_bounds__(256) void normalize_k(const float* __restrict__ f,
                                                   unsigned char* __restrict__ fn) {
    const int row = blockIdx.x;
    const int t = threadIdx.x;
    const float4* fr4 = (const float4*)(f + (size_t)row * DDIM);
    float4 v = make_float4(0.f, 0.f, 0.f, 0.f);
    if (t < 192) v = fr4[t];
    float ss = v.x * v.x + v.y * v.y + v.z * v.z + v.w * v.w;
#pragma unroll
    for (int m = 32; m; m >>= 1) ss += __shfl_xor(ss, m, 64);
    __shared__ float wsum[4];
    if ((t & 63) == 0) wsum[t >> 6] = ss;
    __syncthreads();
    float tot = wsum[0] + wsum[1] + wsum[2] + wsum[3];
    float scale = 16.0f / fmaxf(sqrtf(tot), 1e-8f);
    if (t < 192) {
        int w = __builtin_amdgcn_cvt_pk_fp8_f32(v.x * scale, v.y * scale, 0, 0);
        w = __builtin_amdgcn_cvt_pk_fp8_f32(v.z * scale, v.w * scale, w, 1);
        ((int*)(fn + (size_t)row * DDIM))[t] = w;
    }
}

// ---------------------------------------------------------------------------
// Kernel 2: SYMMETRIC fp8 GEMM (acc = 256*sim) + fused mask reductions.
// R10 = R8 structure (upper-triangle tiles, strip-LDS mirror epilogue, the
// proven win config) with fp8 e4m3 operands: fn fabric bytes halved
// (818->409 MB L3->L2 refill), staging instrs halved, LDS staging 8 KB.
// fp8 16x16x32 MFMA runs at bf16 rate — the win is traffic, not FLOPs.
// Staging swizzle at 16B granularity: chunk c16 of row r at c16^((r>>2)&1);
// ds_read_b64 fragment reads are then worst-case 2-way (free).
// D[m=j][n=i]: j = colBase+wm*64+mf*16+q*4+reg, i = rowBase+wn*64+nf*16+cl.
// ---------------------------------------------------------------------------
__global__ __launch_bounds__(256, 4) void ntxent_main(
        const unsigned char* __restrict__ fn,
        const float* __restrict__ pmask, const float* __restrict__ nmask,
        float* __restrict__ negG, float* __restrict__ sG,
        float* __restrict__ pG) {
    __shared__ __align__(16) char smem[32 * TSTRIDE * 4];   // 16.9 KB
    unsigned char* Is = (unsigned char*)smem;               // 128x32 fp8 (4 KB)
    unsigned char* Js = Is + 4096;                          // 128x32 fp8 (4 KB)
    float* T = (float*)smem;                                // [32][TSTRIDE]

    const int t = threadIdx.x;
    const int lane = t & 63;
    const int wv = t >> 6;
    const int wm = wv & 1;           // wave's j-half
    const int wn = wv >> 1;          // wave's i-half
    const int q  = lane >> 4;
    const int cl = lane & 15;

    // triangular decode: block bt -> (c, r) with c <= r
    const int bt = blockIdx.x;
    int r = (int)((sqrtf(8.0f * (float)bt + 1.0f) - 1.0f) * 0.5f);
    while ((r + 1) * (r + 2) / 2 <= bt) ++r;
    while (r * (r + 1) / 2 > bt) --r;
    const int c = bt - r * (r + 1) / 2;
    const int rowBase = c * 128;     // i-tile
    const int colBase = r * 128;     // j-tile
    const bool offDiag = (c != r);

    floatx4 acc[4][4];            // [mf (j)][nf (i)]
#pragma unroll
    for (int mf = 0; mf < 4; ++mf)
#pragma unroll
        for (int nf = 0; nf < 4; ++nf)
            acc[mf][nf] = (floatx4){0.f, 0.f, 0.f, 0.f};

    // fragment byte offset within a row: k-chunk q>>1 (swizzled) + 8*(q&1)
    for (int k0 = 0; k0 < DDIM; k0 += 32) {
        __syncthreads();
        {
            const int row = t >> 1;                   // 0..127
            const int cg = (t & 1) ^ ((row >> 2) & 1); // swizzled 16B chunk
            const unsigned char* ga = fn + (size_t)(rowBase + row) * DDIM + k0 + cg * 16;
            const unsigned char* gb = fn + (size_t)(colBase + row) * DDIM + k0 + cg * 16;
            __builtin_amdgcn_global_load_lds(
                (const __attribute__((address_space(1))) void*)ga,
                (__attribute__((address_space(3))) void*)(Is + t * 16), 16, 0, 0);
            __builtin_amdgcn_global_load_lds(
                (const __attribute__((address_space(1))) void*)gb,
                (__attribute__((address_space(3))) void*)(Js + t * 16), 16, 0, 0);
        }
        __syncthreads();

        i64 jf[4], if_[4];
#pragma unroll
        for (int mf = 0; mf < 4; ++mf) {
            const int rr = wm * 64 + mf * 16 + cl;
            const int off = rr * 32 + ((((q >> 1) ^ ((rr >> 2) & 1))) << 4) + (q & 1) * 8;
            jf[mf] = *(const i64*)(Js + off);
        }
#pragma unroll
        for (int nf = 0; nf < 4; ++nf) {
            const int rr = wn * 64 + nf * 16 + cl;
            const int off = rr * 32 + ((((q >> 1) ^ ((rr >> 2) & 1))) << 4) + (q & 1) * 8;
            if_[nf] = *(const i64*)(Is + off);
        }
#pragma unroll
        for (int mf = 0; mf < 4; ++mf)
#pragma unroll
            for (int nf = 0; nf < 4; ++nf)
                acc[mf][nf] = __builtin_amdgcn_mfma_f32_16x16x32_fp8_fp8(
                    jf[mf], if_[nf], acc[mf][nf], 0, 0, 0);
    }

    // ---- direct epilogue (rows i, mask[i][j]) ----
    const int col64 = colBase + wm * 64;
    const int jb0 = col64 + q * 4;
#pragma unroll
    for (int nf = 0; nf < 4; ++nf) {
        const int grow = rowBase + wn * 64 + nf * 16 + cl;
        const float* prow = pmask + (size_t)grow * NROWS;
        const float* nrow = nmask + (size_t)grow * NROWS;
        float4 pm4[4], nm4[4];
#pragma unroll
        for (int mf = 0; mf < 4; ++mf) {
            pm4[mf] = *(const float4*)(prow + jb0 + mf * 16);
            nm4[mf] = *(const float4*)(nrow + jb0 + mf * 16);
        }
        float aN = 0.f, aS = 0.f, aP = 0.f;
#pragma unroll
        for (int mf = 0; mf < 4; ++mf) {
            const int jbase = jb0 + mf * 16;
#pragma unroll
            for (int reg = 0; reg < 4; ++reg) {
                float pmv = ((const float*)&pm4[mf])[reg];
                float nmv = ((const float*)&nm4[mf])[reg];
                if (grow == jbase + reg) { pmv = 0.f; nmv = 0.f; }  // diagonal
                float v = acc[mf][nf][reg];
                float e = __builtin_amdgcn_exp2f(v * EK);   // e^(10*sim)
                aN = fmaf(nmv, e, aN);
                aS = fmaf(pmv, v, aS);       // raw units; x SSCALE in final_k
                aP += pmv;
            }
        }
        aN += __shfl_xor(aN, 16, 64);  aN += __shfl_xor(aN, 32, 64);
        aS += __shfl_xor(aS, 16, 64);  aS += __shfl_xor(aS, 32, 64);
        aP += __shfl_xor(aP, 16, 64);  aP += __shfl_xor(aP, 32, 64);
        if (q == 0) {
            atomicAdd(&negG[grow], aN);
            atomicAdd(&sG[grow],   aS);
            atomicAdd(&pG[grow],   aP);
        }
    }

    // ---- mirror epilogue (rows j, mask[j][i]) -- off-diagonal blocks only --
    if (offDiag) {
        const int jl2 = t >> 3;              // 0..31: strip-local j row
        const int iseg = (t & 7) * 16;       // 16-float i segment
#pragma unroll
        for (int st = 0; st < 4; ++st) {
            __syncthreads();                 // strip buffer free
            if (wm == (st >> 1)) {           // waves owning this strip's j's
#pragma unroll
                for (int m2 = 0; m2 < 2; ++m2) {
                    const int mf = (st & 1) * 2 + m2;
#pragma unroll
                    for (int nf = 0; nf < 4; ++nf) {
                        const int i = wn * 64 + nf * 16 + cl;
#pragma unroll
                        for (int reg = 0; reg < 4; ++reg) {
                            const int jl = m2 * 16 + q * 4 + reg;
                            T[jl * TSTRIDE + i] = acc[mf][nf][reg];
                        }
                    }
                }
            }
            __syncthreads();
            const int jg = colBase + st * 32 + jl2;
            const float* prow = pmask + (size_t)jg * NROWS + rowBase + iseg;
            const float* nrow = nmask + (size_t)jg * NROWS + rowBase + iseg;
            float4 pm4[4], nm4[4];
#pragma unroll
            for (int u = 0; u < 4; ++u) {
                pm4[u] = *(const float4*)(prow + u * 4);
                nm4[u] = *(const float4*)(nrow + u * 4);
            }
            const float4* tv = (const float4*)(T + jl2 * TSTRIDE + iseg);
            float aN = 0.f, aS = 0.f, aP = 0.f;
#pragma unroll
            for (int u = 0; u < 4; ++u) {
                float4 v4 = tv[u];
#pragma unroll
                for (int e = 0; e < 4; ++e) {
                    float v = ((const float*)&v4)[e];
                    float pmv = ((const float*)&pm4[u])[e];
                    float nmv = ((const float*)&nm4[u])[e];
                    float ex = __builtin_amdgcn_exp2f(v * EK);
                    aN = fmaf(nmv, ex, aN);
                    aS = fmaf(pmv, v, aS);
                    aP += pmv;
                }
            }
            aN += __shfl_xor(aN, 1, 64); aN += __shfl_xor(aN, 2, 64); aN += __shfl_xor(aN, 4, 64);
            aS += __shfl_xor(aS, 1, 64); aS += __shfl_xor(aS, 2, 64); aS += __shfl_xor(aS, 4, 64);
            aP += __shfl_xor(aP, 1, 64); aP += __shfl_xor(aP, 2, 64); aP += __shfl_xor(aP, 4, 64);
            if ((t & 7) == 0) {
                atomicAdd(&negG[jg], aN);
                atomicAdd(&sG[jg],   aS);
                atomicAdd(&pG[jg],   aP);
            }
        }
    }
}

// ---------------------------------------------------------------------------
// Kernel 3: per-row loss assembly + mean
// loss_i = (P*log(neg) - SSCALE*S_raw)/P (P>0 else 0);  out = mean
// ---------------------------------------------------------------------------
__global__ __launch_bounds__(1024) void final_k(const float* __restrict__ negG,
        const float* __restrict__ sG, const float* __restrict__ pG,
        float* __restrict__ out) {
    const int t = threadIdx.x;
    float sum = 0.f;
    for (int i = t; i < NROWS; i += 1024) {
        float P = pG[i];
        if (P > 0.f) {
            sum += (P * logf(negG[i]) - SSCALE * sG[i]) / P;
        }
    }
#pragma unroll
    for (int m = 32; m; m >>= 1) sum += __shfl_xor(sum, m, 64);
    __shared__ float wsum[16];
    if ((t & 63) == 0) wsum[t >> 6] = sum;
    __syncthreads();
    if (t < 16) {
        float v = wsum[t];
#pragma unroll
        for (int m = 8; m; m >>= 1) v += __shfl_xor(v, m, 16);
        if (t == 0) out[0] = v / (float)NROWS;
    }
}

// ---------------------------------------------------------------------------
extern "C" void kernel_launch(void* const* d_in, const int* in_sizes, int n_in,
                              void* d_out, int out_size, void* d_ws, size_t ws_size,
                              hipStream_t stream) {
    const float* feat  = (const float*)d_in[0];
    const float* pmask = (const float*)d_in[1];
    const float* nmask = (const float*)d_in[2];
    float* out = (float*)d_out;

    char* ws = (char*)d_ws;
    unsigned char* fn = (unsigned char*)ws;                      // 6,291,456 B
    float* negG = (float*)(ws + 6291456);
    float* sG = negG + NROWS;
    float* pG = sG + NROWS;

    // zero all three row accumulators (ws is re-poisoned before every launch)
    hipMemsetAsync(negG, 0, 3 * NROWS * sizeof(float), stream);

    normalize_k<<<NROWS, 256, 0, stream>>>(feat, fn);

    ntxent_main<<<2080, 256, 0, stream>>>(fn, pmask, nmask, negG, sG, pG);

    final_k<<<1, 1024, 0, stream>>>(negG, sG, pG, out);
}

// Round 11
// 589.569 us; speedup vs baseline: 1.4059x; 1.0018x over previous
//
#include <hip/hip_runtime.h>
#include <hip/hip_bf16.h>

#define NROWS 8192
#define DDIM 768

typedef float floatx4 __attribute__((ext_vector_type(4)));  // MFMA C/D
typedef long i64;                                           // fp8 MFMA A/B frag
#define TSTRIDE 132   // transpose LDS row stride (floats)
// acc holds 256*sim (fn scaled by 16 per side). e^(10*sim) = exp2(acc*EK):
#define EK 0.05635527503472514f      // = log2(e) * 10 / 256
#define SSCALE 0.390625f             // = 10 / 256 (applied in final_k)

// ---------------------------------------------------------------------------
// Kernel 1: row-normalize features (fp32 in) -> fp8 e4m3 rows, scaled x16
// ---------------------------------------------------------------------------
__global__ __launch_bounds__(256) void normalize_k(const float* __restrict__ f,
                                                   unsigned char* __restrict__ fn) {
    const int row = blockIdx.x;
    const int t = threadIdx.x;
    const float4* fr4 = (const float4*)(f + (size_t)row * DDIM);
    float4 v = make_float4(0.f, 0.f, 0.f, 0.f);
    if (t < 192) v = fr4[t];
    float ss = v.x * v.x + v.y * v.y + v.z * v.z + v.w * v.w;
#pragma unroll
    for (int m = 32; m; m >>= 1) ss += __shfl_xor(ss, m, 64);
    __shared__ float wsum[4];
    if ((t & 63) == 0) wsum[t >> 6] = ss;
    __syncthreads();
    float tot = wsum[0] + wsum[1] + wsum[2] + wsum[3];
    float scale = 16.0f / fmaxf(sqrtf(tot), 1e-8f);
    if (t < 192) {
        int w = __builtin_amdgcn_cvt_pk_fp8_f32(v.x * scale, v.y * scale, 0, 0);
        w = __builtin_amdgcn_cvt_pk_fp8_f32(v.z * scale, v.w * scale, w, 1);
        ((int*)(fn + (size_t)row * DDIM))[t] = w;
    }
}

// ---------------------------------------------------------------------------
// Kernel 2: SYMMETRIC fp8 GEMM (acc = 256*sim) + fused mask reductions.
// R11 = R10 with LDS cut 16.9 -> 8.45 KB (mirror strips 32 -> 16 rows, fp8
// staging aliased into T): occupancy ledger says LDS pool for occupancy is
// ~64 KB/CU, so <16 KB buys the 4th resident block (register cap: acc 64
// AGPR + 64 VGPR = 128 -> 16 waves). TLP attacks the diagnosed stall-bound
// regime (R10: all pipes <10% busy; byte cuts did nothing).
// D[m=j][n=i]: j = colBase+wm*64+mf*16+q*4+reg, i = rowBase+wn*64+nf*16+cl.
// ---------------------------------------------------------------------------
__global__ __launch_bounds__(256, 4) void ntxent_main(
        const unsigned char* __restrict__ fn,
        const float* __restrict__ pmask, const float* __restrict__ nmask,
        float* __restrict__ negG, float* __restrict__ sG,
        float* __restrict__ pG) {
    __shared__ __align__(16) char smem[16 * TSTRIDE * 4];   // 8448 B
    unsigned char* Is = (unsigned char*)smem;               // 128x32 fp8 (4 KB)
    unsigned char* Js = Is + 4096;                          // 128x32 fp8 (4 KB)
    float* T = (float*)smem;                                // [16][TSTRIDE]

    const int t = threadIdx.x;
    const int lane = t & 63;
    const int wv = t >> 6;
    const int wm = wv & 1;           // wave's j-half
    const int wn = wv >> 1;          // wave's i-half
    const int q  = lane >> 4;
    const int cl = lane & 15;

    // triangular decode: block bt -> (c, r) with c <= r
    const int bt = blockIdx.x;
    int r = (int)((sqrtf(8.0f * (float)bt + 1.0f) - 1.0f) * 0.5f);
    while ((r + 1) * (r + 2) / 2 <= bt) ++r;
    while (r * (r + 1) / 2 > bt) --r;
    const int c = bt - r * (r + 1) / 2;
    const int rowBase = c * 128;     // i-tile
    const int colBase = r * 128;     // j-tile
    const bool offDiag = (c != r);

    floatx4 acc[4][4];            // [mf (j)][nf (i)]
#pragma unroll
    for (int mf = 0; mf < 4; ++mf)
#pragma unroll
        for (int nf = 0; nf < 4; ++nf)
            acc[mf][nf] = (floatx4){0.f, 0.f, 0.f, 0.f};

    for (int k0 = 0; k0 < DDIM; k0 += 32) {
        __syncthreads();
        {
            const int row = t >> 1;                    // 0..127
            const int cg = (t & 1) ^ ((row >> 2) & 1); // swizzled 16B chunk
            const unsigned char* ga = fn + (size_t)(rowBase + row) * DDIM + k0 + cg * 16;
            const unsigned char* gb = fn + (size_t)(colBase + row) * DDIM + k0 + cg * 16;
            __builtin_amdgcn_global_load_lds(
                (const __attribute__((address_space(1))) void*)ga,
                (__attribute__((address_space(3))) void*)(Is + t * 16), 16, 0, 0);
            __builtin_amdgcn_global_load_lds(
                (const __attribute__((address_space(1))) void*)gb,
                (__attribute__((address_space(3))) void*)(Js + t * 16), 16, 0, 0);
        }
        __syncthreads();

        i64 jf[4], if_[4];
#pragma unroll
        for (int mf = 0; mf < 4; ++mf) {
            const int rr = wm * 64 + mf * 16 + cl;
            const int off = rr * 32 + ((((q >> 1) ^ ((rr >> 2) & 1))) << 4) + (q & 1) * 8;
            jf[mf] = *(const i64*)(Js + off);
        }
#pragma unroll
        for (int nf = 0; nf < 4; ++nf) {
            const int rr = wn * 64 + nf * 16 + cl;
            const int off = rr * 32 + ((((q >> 1) ^ ((rr >> 2) & 1))) << 4) + (q & 1) * 8;
            if_[nf] = *(const i64*)(Is + off);
        }
#pragma unroll
        for (int mf = 0; mf < 4; ++mf)
#pragma unroll
            for (int nf = 0; nf < 4; ++nf)
                acc[mf][nf] = __builtin_amdgcn_mfma_f32_16x16x32_fp8_fp8(
                    jf[mf], if_[nf], acc[mf][nf], 0, 0, 0);
    }

    // ---- direct epilogue (rows i, mask[i][j]) ----
    const int col64 = colBase + wm * 64;
    const int jb0 = col64 + q * 4;
#pragma unroll
    for (int nf = 0; nf < 4; ++nf) {
        const int grow = rowBase + wn * 64 + nf * 16 + cl;
        const float* prow = pmask + (size_t)grow * NROWS;
        const float* nrow = nmask + (size_t)grow * NROWS;
        float4 pm4[4], nm4[4];
#pragma unroll
        for (int mf = 0; mf < 4; ++mf) {
            pm4[mf] = *(const float4*)(prow + jb0 + mf * 16);
            nm4[mf] = *(const float4*)(nrow + jb0 + mf * 16);
        }
        float aN = 0.f, aS = 0.f, aP = 0.f;
#pragma unroll
        for (int mf = 0; mf < 4; ++mf) {
            const int jbase = jb0 + mf * 16;
#pragma unroll
            for (int reg = 0; reg < 4; ++reg) {
                float pmv = ((const float*)&pm4[mf])[reg];
                float nmv = ((const float*)&nm4[mf])[reg];
                if (grow == jbase + reg) { pmv = 0.f; nmv = 0.f; }  // diagonal
                float v = acc[mf][nf][reg];
                float e = __builtin_amdgcn_exp2f(v * EK);   // e^(10*sim)
                aN = fmaf(nmv, e, aN);
                aS = fmaf(pmv, v, aS);       // raw units; x SSCALE in final_k
                aP += pmv;
            }
        }
        aN += __shfl_xor(aN, 16, 64);  aN += __shfl_xor(aN, 32, 64);
        aS += __shfl_xor(aS, 16, 64);  aS += __shfl_xor(aS, 32, 64);
        aP += __shfl_xor(aP, 16, 64);  aP += __shfl_xor(aP, 32, 64);
        if (q == 0) {
            atomicAdd(&negG[grow], aN);
            atomicAdd(&sG[grow],   aS);
            atomicAdd(&pG[grow],   aP);
        }
    }

    // ---- mirror epilogue (rows j, mask[j][i]) -- 16-row strips x8 ----
    if (offDiag) {
        const int jl2 = t >> 4;              // 0..15: strip-local j row
        const int iseg = (t & 15) * 8;       // 8-float i segment
#pragma unroll
        for (int st = 0; st < 8; ++st) {
            __syncthreads();                 // strip buffer free
            if (wm == (st >> 2)) {           // wave pair owning this strip
                const int mf = st & 3;
#pragma unroll
                for (int nf = 0; nf < 4; ++nf) {
                    const int i = wn * 64 + nf * 16 + cl;
#pragma unroll
                    for (int reg = 0; reg < 4; ++reg) {
                        const int jl = q * 4 + reg;         // 0..15
                        T[jl * TSTRIDE + i] = acc[mf][nf][reg];
                    }
                }
            }
            __syncthreads();
            const int jg = colBase + st * 16 + jl2;
            const float* prow = pmask + (size_t)jg * NROWS + rowBase + iseg;
            const float* nrow = nmask + (size_t)jg * NROWS + rowBase + iseg;
            float4 pm4[2], nm4[2];
            pm4[0] = *(const float4*)(prow);     pm4[1] = *(const float4*)(prow + 4);
            nm4[0] = *(const float4*)(nrow);     nm4[1] = *(const float4*)(nrow + 4);
            const float4* tv = (const float4*)(T + jl2 * TSTRIDE + iseg);
            float aN = 0.f, aS = 0.f, aP = 0.f;
#pragma unroll
            for (int u = 0; u < 2; ++u) {
                float4 v4 = tv[u];
#pragma unroll
                for (int e = 0; e < 4; ++e) {
                    float v = ((const float*)&v4)[e];
                    float pmv = ((const float*)&pm4[u])[e];
                    float nmv = ((const float*)&nm4[u])[e];
                    float ex = __builtin_amdgcn_exp2f(v * EK);
                    aN = fmaf(nmv, ex, aN);
                    aS = fmaf(pmv, v, aS);
                    aP += pmv;
                }
            }
            aN += __shfl_xor(aN, 1, 64); aN += __shfl_xor(aN, 2, 64);
            aN += __shfl_xor(aN, 4, 64); aN += __shfl_xor(aN, 8, 64);
            aS += __shfl_xor(aS, 1, 64); aS += __shfl_xor(aS, 2, 64);
            aS += __shfl_xor(aS, 4, 64); aS += __shfl_xor(aS, 8, 64);
            aP += __shfl_xor(aP, 1, 64); aP += __shfl_xor(aP, 2, 64);
            aP += __shfl_xor(aP, 4, 64); aP += __shfl_xor(aP, 8, 64);
            if ((t & 15) == 0) {
                atomicAdd(&negG[jg], aN);
                atomicAdd(&sG[jg],   aS);
                atomicAdd(&pG[jg],   aP);
            }
        }
    }
}

// ---------------------------------------------------------------------------
// Kernel 3: per-row loss assembly + mean
// loss_i = (P*log(neg) - SSCALE*S_raw)/P (P>0 else 0);  out = mean
// ---------------------------------------------------------------------------
__global__ __launch_bounds__(1024) void final_k(const float* __restrict__ negG,
        const float* __restrict__ sG, const float* __restrict__ pG,
        float* __restrict__ out) {
    const int t = threadIdx.x;
    float sum = 0.f;
    for (int i = t; i < NROWS; i += 1024) {
        float P = pG[i];
        if (P > 0.f) {
            sum += (P * logf(negG[i]) - SSCALE * sG[i]) / P;
        }
    }
#pragma unroll
    for (int m = 32; m; m >>= 1) sum += __shfl_xor(sum, m, 64);
    __shared__ float wsum[16];
    if ((t & 63) == 0) wsum[t >> 6] = sum;
    __syncthreads();
    if (t < 16) {
        float v = wsum[t];
#pragma unroll
        for (int m = 8; m; m >>= 1) v += __shfl_xor(v, m, 16);
        if (t == 0) out[0] = v / (float)NROWS;
    }
}

// ---------------------------------------------------------------------------
extern "C" void kernel_launch(void* const* d_in, const int* in_sizes, int n_in,
                              void* d_out, int out_size, void* d_ws, size_t ws_size,
                              hipStream_t stream) {
    const float* feat  = (const float*)d_in[0];
    const float* pmask = (const float*)d_in[1];
    const float* nmask = (const float*)d_in[2];
    float* out = (float*)d_out;

    char* ws = (char*)d_ws;
    unsigned char* fn = (unsigned char*)ws;                      // 6,291,456 B
    float* negG = (float*)(ws + 6291456);
    float* sG = negG + NROWS;
    float* pG = sG + NROWS;

    // zero all three row accumulators (ws is re-poisoned before every launch)
    hipMemsetAsync(negG, 0, 3 * NROWS * sizeof(float), stream);

    normalize_k<<<NROWS, 256, 0, stream>>>(feat, fn);

    ntxent_main<<<2080, 256, 0, stream>>>(fn, pmask, nmask, negG, sG, pG);

    final_k<<<1, 1024, 0, stream>>>(negG, sG, pG, out);
}